// Round 1
// baseline (942.102 us; speedup 1.0000x reference)
//
#include <hip/hip_runtime.h>
#include <cmath>

#define NDIM   4096
#define BATCH  32
#define TSTEPS 600

// tanh(x) = 1 - 2/(e^{2x}+1); e^{2x} = 2^{x * 2*log2(e)}
__device__ __forceinline__ float fast_tanh(float x) {
    float y = __builtin_amdgcn_exp2f(x * 2.8853900817779268f);
    return 1.0f - 2.0f * __builtin_amdgcn_rcpf(y + 1.0f);
}

// One block per batch. h[4] per thread in registers (1024 threads * 4 = N).
// Per step: tanh -> rank-2 partial dots -> wave shuffle reduce -> LDS cross-wave
// reduce (parity double-buffered, ONE barrier per step) -> elementwise update ->
// streamed store. Noise prefetched 4 steps ahead into registers.
__global__ __launch_bounds__(1024, 1)
void rnn_lowrank_kernel(const float* __restrict__ inp,   // [B,T,1]
                        const float* __restrict__ Iv,    // [N,1]
                        const float* __restrict__ U,     // [N,2]
                        const float* __restrict__ V,     // [N,2]
                        const float* __restrict__ nr,    // [B,T,N]
                        const float* __restrict__ ninp,  // [B,T,1]
                        float* __restrict__ out)         // [B,T+1,N]
{
    const int b    = blockIdx.x;
    const int tid  = threadIdx.x;
    const int lane = tid & 63;
    const int wid  = tid >> 6;

    __shared__ float  e_lds[TSTEPS];
    __shared__ float2 sm[2][16];

    // effective input per (b,t): inp + sig_inp*sqrt(2*dt/tau) * ninp
    for (int t = tid; t < TSTEPS; t += 1024)
        e_lds[t] = inp[b * TSTEPS + t] + 0.004472135955f * ninp[b * TSTEPS + t];

    const int n0 = tid * 4;
    const float A_INVN = 0.1f / 4096.0f;   // alpha / N

    // per-thread constant fragments
    const float4 uA = *(const float4*)(U + n0 * 2);       // U[n0][0..1], U[n0+1][0..1]
    const float4 uB = *(const float4*)(U + n0 * 2 + 4);
    const float4 vA = *(const float4*)(V + n0 * 2);
    const float4 vB = *(const float4*)(V + n0 * 2 + 4);
    const float4 iv = *(const float4*)(Iv + n0);

    float c0[4], c1[4], cI[4], v0[4], v1[4];
    c0[0] = A_INVN * uA.x; c1[0] = A_INVN * uA.y;
    c0[1] = A_INVN * uA.z; c1[1] = A_INVN * uA.w;
    c0[2] = A_INVN * uB.x; c1[2] = A_INVN * uB.y;
    c0[3] = A_INVN * uB.z; c1[3] = A_INVN * uB.w;
    v0[0] = vA.x; v1[0] = vA.y; v0[1] = vA.z; v1[1] = vA.w;
    v0[2] = vB.x; v1[2] = vB.y; v0[3] = vB.z; v1[3] = vB.w;
    cI[0] = 0.1f * iv.x; cI[1] = 0.1f * iv.y; cI[2] = 0.1f * iv.z; cI[3] = 0.1f * iv.w;

    // h0 row (t=0) is zeros
    float4* out4 = (float4*)(out + (size_t)b * (TSTEPS + 1) * NDIM);
    out4[tid] = make_float4(0.f, 0.f, 0.f, 0.f);

    const float4* nr4 = (const float4*)(nr + (size_t)b * TSTEPS * NDIM);

    // 4-deep register prefetch of recurrent noise
    float4 pre0 = nr4[0 * 1024 + tid];
    float4 pre1 = nr4[1 * 1024 + tid];
    float4 pre2 = nr4[2 * 1024 + tid];
    float4 pre3 = nr4[3 * 1024 + tid];

    float h0 = 0.f, h1 = 0.f, h2 = 0.f, h3 = 0.f;

    __syncthreads();  // e_lds ready

    const float ANR = 0.1f * 0.22360679775f;  // alpha * sig_rec*sqrt(2*tau/dt)

    for (int t0 = 0; t0 < TSTEPS; t0 += 4) {
        #pragma unroll
        for (int j = 0; j < 4; ++j) {
            const int t = t0 + j;

            // consume prefetched noise; issue prefetch for t+4
            float4 nv = (j == 0) ? pre0 : (j == 1) ? pre1 : (j == 2) ? pre2 : pre3;
            int tp = t + 4; if (tp >= TSTEPS) tp = TSTEPS - 1;
            float4 nl = nr4[tp * 1024 + tid];
            if (j == 0) pre0 = nl; else if (j == 1) pre1 = nl;
            else if (j == 2) pre2 = nl; else pre3 = nl;

            // rank-2 partial dot of tanh(h) with V
            float p0 = 0.f, p1 = 0.f;
            {
                float fr;
                fr = fast_tanh(h0); p0 += fr * v0[0]; p1 += fr * v1[0];
                fr = fast_tanh(h1); p0 += fr * v0[1]; p1 += fr * v1[1];
                fr = fast_tanh(h2); p0 += fr * v0[2]; p1 += fr * v1[2];
                fr = fast_tanh(h3); p0 += fr * v0[3]; p1 += fr * v1[3];
            }

            // wave-level butterfly reduce (64 lanes)
            #pragma unroll
            for (int m = 32; m > 0; m >>= 1) {
                p0 += __shfl_xor(p0, m, 64);
                p1 += __shfl_xor(p1, m, 64);
            }

            // cross-wave reduce via LDS, parity double-buffered: 1 barrier/step
            const int par = t & 1;
            if (lane == 0) sm[par][wid] = make_float2(p0, p1);
            __syncthreads();
            float s0 = 0.f, s1 = 0.f;
            #pragma unroll
            for (int w = 0; w < 16; ++w) { float2 q = sm[par][w]; s0 += q.x; s1 += q.y; }

            // h_{t+1} = 0.9 h + (a/N)(s0 U0 + s1 U1) + a*e*I + a*0.2236*nrec
            const float e = e_lds[t];
            h0 = 0.9f * h0 + s0 * c0[0] + s1 * c1[0] + e * cI[0] + ANR * nv.x;
            h1 = 0.9f * h1 + s0 * c0[1] + s1 * c1[1] + e * cI[1] + ANR * nv.y;
            h2 = 0.9f * h2 + s0 * c0[2] + s1 * c1[2] + e * cI[2] + ANR * nv.z;
            h3 = 0.9f * h3 + s0 * c0[3] + s1 * c1[3] + e * cI[3] + ANR * nv.w;

            out4[(t + 1) * 1024 + tid] = make_float4(h0, h1, h2, h3);
        }
    }
}

extern "C" void kernel_launch(void* const* d_in, const int* in_sizes, int n_in,
                              void* d_out, int out_size, void* d_ws, size_t ws_size,
                              hipStream_t stream) {
    const float* inp  = (const float*)d_in[0];  // [B,T,1]
    const float* Iv   = (const float*)d_in[1];  // [N,1]
    const float* U    = (const float*)d_in[2];  // [N,2]
    const float* V    = (const float*)d_in[3];  // [N,2]
    const float* nr   = (const float*)d_in[4];  // [B,T,N]
    const float* ninp = (const float*)d_in[5];  // [B,T,1]
    float* out = (float*)d_out;                 // [B,T+1,N]

    rnn_lowrank_kernel<<<dim3(BATCH), dim3(1024), 0, stream>>>(
        inp, Iv, U, V, nr, ninp, out);
}